// Round 13
// baseline (679.423 us; speedup 1.0000x reference)
//
#include <hip/hip_runtime.h>
#include <hip/hip_bf16.h>

#define N_NODES 100000
#define N_FEAT  1433
#define NKT1    46       // k-tiles of 32 for K=1433->1472
#define NBANDS  (N_NODES / 16)   // 6250 bands of 16 rows
#define HID     64
#define NCLS    7
#define SCAN_BLK 1024
#define NBLK    ((N_NODES + SCAN_BLK - 1) / SCAN_BLK)   // 98

typedef __attribute__((ext_vector_type(8))) short short8v;
typedef __attribute__((ext_vector_type(4))) float f32x4;

__device__ __forceinline__ unsigned short f2bf(float v) {
    unsigned u = __float_as_uint(v);
    unsigned r = (u + 0x7FFFu + ((u >> 16) & 1u)) >> 16;   // RNE
    return (unsigned short)r;
}
__device__ __forceinline__ float bf2f(unsigned short h) {
    return __uint_as_float(((unsigned)h) << 16);
}

// packed f32x2 -> bf16x2 via v_cvt_pk_bf16_f32 (RNE)
__device__ __forceinline__ unsigned pk2(float a, float b) {
    union { __hip_bfloat162 h2; unsigned u; } cv;
    cv.h2 = __float22bfloat162_rn(make_float2(a, b));
    return cv.u;
}
__device__ __forceinline__ short8v cvt8(const float* v) {
    union { unsigned u[4]; short8v s; } r;
#pragma unroll
    for (int i = 0; i < 4; ++i) r.u[i] = pk2(v[2 * i], v[2 * i + 1]);
    return r.s;
}

// ---------------- W -> fragment-major bf16 hi/lo (device body) ----------------
__device__ __forceinline__
void convert_body(const float* __restrict__ W, int K, int ncols, int nfc, int tid, int total,
                  unsigned short* __restrict__ wfh, unsigned short* __restrict__ wfl) {
    if (tid >= total) return;
    int rem  = tid % (nfc * 64);
    int kt   = tid / (nfc * 64);
    int nf   = rem >> 6;
    int lane = rem & 63;
    int n  = nf * 16 + (lane & 15);
    int kb = kt * 32 + ((lane >> 4) << 3);
    short8v hi, lo;
#pragma unroll
    for (int j = 0; j < 8; ++j) {
        int k = kb + j;
        float v = (k < K && n < ncols) ? W[(size_t)k * ncols + n] : 0.f;
        unsigned short h = f2bf(v);
        hi[j] = (short)h;
        lo[j] = (short)f2bf(v - bf2f(h));
    }
    *(short8v*)(wfh + (size_t)tid * 8) = hi;
    *(short8v*)(wfl + (size_t)tid * 8) = lo;
}

// ---------------- X band -> fragment-major bf16 (streaming, LDS transpose) ----------------
// xf[((band*46 + kt)*64 + lane)] (16B frag): elem j = X[band*16+(lane&15)][kt*32+(lane>>4)*8+j]
__device__ __forceinline__
void xconvert_body(int band, const float* __restrict__ X, unsigned short* __restrict__ xf,
                   float (*xs)[260]) {
    const int t = threadIdx.x;
#pragma unroll 1
    for (int chunk = 0; chunk < 6; ++chunk) {
        int c0 = chunk * 256;
        __syncthreads();
#pragma unroll
        for (int r = 0; r < 16; ++r) {
            int col = c0 + t;
            float v = (col < N_FEAT) ? X[(size_t)(band * 16 + r) * N_FEAT + col] : 0.f;
            xs[r][t] = v;
        }
        __syncthreads();
#pragma unroll
        for (int half = 0; half < 2; ++half) {
            int idx  = half * 256 + t;      // 0..511
            int ktl  = idx >> 6;            // 0..7
            int lane = idx & 63;
            int kt   = chunk * 8 + ktl;
            if (kt >= NKT1) continue;       // chunk 5 covers kt 40..45 only
            float v[8];
            int cbase = ktl * 32 + ((lane >> 4) << 3);
#pragma unroll
            for (int j = 0; j < 8; ++j) v[j] = xs[lane & 15][cbase + j];
            *(short8v*)(xf + (size_t)((band * NKT1 + kt) * 64 + lane) * 8) = cvt8(v);
        }
    }
}

// ---------------- prep1: [x-convert | w-converts | hist] block-role-split ----------------
#define XCV_BLKS NBANDS        // 6250
#define WCV_BLKS 53
__global__ __launch_bounds__(256)
void prep1(const float* __restrict__ X, unsigned short* __restrict__ xf,
           const float* __restrict__ W1,  unsigned short* w1fh, unsigned short* w1fl,
           const float* __restrict__ W2,  unsigned short* w2fh, unsigned short* w2fl,
           const float* __restrict__ Wf1, unsigned short* wf1h, unsigned short* wf1l,
           const float* __restrict__ Wf2, unsigned short* wf2h, unsigned short* wf2l,
           const float* __restrict__ Wf3, unsigned short* wf3h, unsigned short* wf3l,
           const int* __restrict__ dst, int* __restrict__ counts, int E) {
    __shared__ float xs[16][260];
    int b = blockIdx.x;
    int t = threadIdx.x;
    if (b < XCV_BLKS) { xconvert_body(b, X, xf, xs); return; }
    b -= XCV_BLKS;
    if (b >= WCV_BLKS) {
        int e = (b - WCV_BLKS) * 256 + t;
        if (e < E) atomicAdd(&counts[dst[e]], 1);
        return;
    }
    if (b < 46)       convert_body(W1,  N_FEAT, 64, 4, b * 256 + t,        NKT1 * 4 * 64, w1fh, w1fl);
    else if (b < 48)  convert_body(W2,  64, 64,   4, (b - 46) * 256 + t,   2 * 4 * 64,    w2fh, w2fl);
    else if (b < 50)  convert_body(Wf1, 64, 64,   4, (b - 48) * 256 + t,   2 * 4 * 64,    wf1h, wf1l);
    else if (b < 52)  convert_body(Wf2, 64, 64,   4, (b - 50) * 256 + t,   2 * 4 * 64,    wf2h, wf2l);
    else              convert_body(Wf3, 64, NCLS, 1, (b - 52) * 256 + t,   2 * 1 * 64,    wf3h, wf3l);
}

// ---------------- 3-phase parallel exclusive scan (p1 fuses dinv) ----------------
__global__ __launch_bounds__(SCAN_BLK)
void scan_p1d(const int* __restrict__ counts, int* __restrict__ local_ex,
              int* __restrict__ blocksum, float* __restrict__ dinv, int n) {
    __shared__ int sh[SCAN_BLK];
    int t = threadIdx.x;
    int i = blockIdx.x * SCAN_BLK + t;
    int v = (i < n) ? counts[i] : 0;
    if (i < n) dinv[i] = rsqrtf((float)(v + 1));   // +1 = self loop
    sh[t] = v;
    __syncthreads();
    for (int off = 1; off < SCAN_BLK; off <<= 1) {
        int u = (t >= off) ? sh[t - off] : 0;
        __syncthreads();
        sh[t] += u;
        __syncthreads();
    }
    if (i < n) local_ex[i] = sh[t] - v;      // exclusive
    if (t == SCAN_BLK - 1) blocksum[blockIdx.x] = sh[t];
}

__global__ __launch_bounds__(128)
void scan_p2(int* __restrict__ blocksum, int* __restrict__ blockoff,
             int* __restrict__ offsets_last, int nb) {
    __shared__ int sh[128];
    int t = threadIdx.x;
    int v = (t < nb) ? blocksum[t] : 0;
    sh[t] = v;
    __syncthreads();
    for (int off = 1; off < 128; off <<= 1) {
        int u = (t >= off) ? sh[t - off] : 0;
        __syncthreads();
        sh[t] += u;
        __syncthreads();
    }
    if (t < nb) blockoff[t] = sh[t] - v;
    if (t == nb - 1) *offsets_last = sh[t];
}

__global__ __launch_bounds__(SCAN_BLK)
void scan_p3(const int* __restrict__ local_ex, const int* __restrict__ blockoff,
             int* __restrict__ offsets, int* __restrict__ cursor, int n) {
    int i = blockIdx.x * SCAN_BLK + threadIdx.x;
    if (i < n) {
        int v = local_ex[i] + blockoff[blockIdx.x];
        offsets[i] = v;
        cursor[i]  = v;
    }
}

// ---------------- GEMM1 body v11: fragment-major A (pure sequential 16B/lane loads) ----------------
__device__ __forceinline__
void gemm_xw_body(int blk, const unsigned short* __restrict__ xf,
                  const unsigned short* __restrict__ wfh,
                  unsigned short* __restrict__ H16, int M) {
    const int t    = threadIdx.x;
    const int lane = t & 63;
    const int w    = t >> 6;
    const int m0   = blk * 128 + w * 32;
    const int lrow = lane & 15;
    int b0 = m0 >> 4;
    if (b0 > NBANDS - 2) b0 = NBANDS - 2;   // tail waves: clamp reads, writes guarded by m0

    f32x4 acc[2][4];
#pragma unroll
    for (int i = 0; i < 2; ++i)
#pragma unroll
        for (int j = 0; j < 4; ++j) acc[i][j] = (f32x4){0.f, 0.f, 0.f, 0.f};

    const short8v* a0 = (const short8v*)xf + (size_t)(b0 * NKT1) * 64 + lane;
    const short8v* a1 = a0 + (size_t)NKT1 * 64;
    const short8v* bh = (const short8v*)wfh + lane;

    // kt 0..44 (kt=45 is all-pad-zero on both sides: skip)
#pragma unroll 4
    for (int kt = 0; kt < 45; ++kt) {
        short8v aH[2], bH[4];
        aH[0] = a0[kt * 64];
        aH[1] = a1[kt * 64];
#pragma unroll
        for (int nf = 0; nf < 4; ++nf)
            bH[nf] = bh[(kt * 4 + nf) * 64];
#pragma unroll
        for (int mf = 0; mf < 2; ++mf)
#pragma unroll
            for (int nf = 0; nf < 4; ++nf)
                acc[mf][nf] = __builtin_amdgcn_mfma_f32_16x16x32_bf16(aH[mf], bH[nf], acc[mf][nf], 0, 0, 0);
    }
    // C: col = lane&15, row = (lane>>4)*4 + reg
#pragma unroll
    for (int mf = 0; mf < 2; ++mf)
#pragma unroll
        for (int r = 0; r < 4; ++r) {
            int row = m0 + mf * 16 + ((lane >> 4) << 2) + r;
            if (row < M) {
#pragma unroll
                for (int nf = 0; nf < 4; ++nf)
                    H16[(size_t)row * 64 + nf * 16 + lrow] = f2bf(acc[mf][nf][r]);
            }
        }
}

// ---------------- scatter body: single int2 payload (src, weight) ----------------
__device__ __forceinline__
void scatter_body(int blk, const int* __restrict__ src, const int* __restrict__ dst,
                  const float* __restrict__ dinv, int* __restrict__ cursor,
                  int2* __restrict__ pay, int E) {
    int e = blk * 256 + threadIdx.x;
    if (e >= E) return;
    int s = src[e], d = dst[e];
    int pos = atomicAdd(&cursor[d], 1);
    pay[pos] = make_int2(s, __float_as_int(dinv[s] * dinv[d]));
}

// ---------------- mega2: [gemm | scatter] block-role-split ----------------
__global__ __launch_bounds__(256)
void mega2(const unsigned short* __restrict__ xf, const unsigned short* __restrict__ w1fh,
           unsigned short* __restrict__ H16, int M, int GB,
           const int* __restrict__ src, const int* __restrict__ dst,
           const float* __restrict__ dinv, int* __restrict__ cursor,
           int2* __restrict__ pay, int E) {
    int b = blockIdx.x;
    if (b < GB) gemm_xw_body(b, xf, w1fh, H16, M);
    else        scatter_body(b - GB, src, dst, dinv, cursor, pay, E);
}

// ---------------- GEMM2 v3: [M,64] f32 @ [64,64], cvt_pk, frag-major W2 hi/lo ----------------
__global__ __launch_bounds__(256)
void gemm_hid_v3(const float* __restrict__ A,
                 const unsigned short* __restrict__ wfh,
                 const unsigned short* __restrict__ wfl,
                 unsigned short* __restrict__ H16, int M) {
    const int t    = threadIdx.x;
    const int lane = t & 63;
    const int w    = t >> 6;
    const int m0   = blockIdx.x * 128 + w * 32;
    const int lrow = lane & 15;
    const int koff = (lane >> 4) * 8;

    f32x4 acc[2][4];
#pragma unroll
    for (int i = 0; i < 2; ++i)
#pragma unroll
        for (int j = 0; j < 4; ++j) acc[i][j] = (f32x4){0.f, 0.f, 0.f, 0.f};

    const float* a0 = A + (size_t)min(m0 + lrow,      M - 1) * 64;
    const float* a1 = A + (size_t)min(m0 + 16 + lrow, M - 1) * 64;
    const short8v* bh = (const short8v*)wfh + lane;
    const short8v* bl = (const short8v*)wfl + lane;

#pragma unroll
    for (int kt = 0; kt < 2; ++kt) {
        int kk = kt * 32 + koff;
        short8v aH[2], bH[4], bL[4];
        float v0[8], v1[8];
        __builtin_memcpy(v0, a0 + kk, 32);
        __builtin_memcpy(v1, a1 + kk, 32);
        aH[0] = cvt8(v0);
        aH[1] = cvt8(v1);
#pragma unroll
        for (int nf = 0; nf < 4; ++nf) {
            bH[nf] = bh[(kt * 4 + nf) * 64];
            bL[nf] = bl[(kt * 4 + nf) * 64];
        }
#pragma unroll
        for (int mf = 0; mf < 2; ++mf)
#pragma unroll
            for (int nf = 0; nf < 4; ++nf) {
                acc[mf][nf] = __builtin_amdgcn_mfma_f32_16x16x32_bf16(aH[mf], bH[nf], acc[mf][nf], 0, 0, 0);
                acc[mf][nf] = __builtin_amdgcn_mfma_f32_16x16x32_bf16(aH[mf], bL[nf], acc[mf][nf], 0, 0, 0);
            }
    }
#pragma unroll
    for (int mf = 0; mf < 2; ++mf)
#pragma unroll
        for (int r = 0; r < 4; ++r) {
            int row = m0 + mf * 16 + ((lane >> 4) << 2) + r;
            if (row < M) {
#pragma unroll
                for (int nf = 0; nf < 4; ++nf)
                    H16[(size_t)row * 64 + nf * 16 + lrow] = f2bf(acc[mf][nf][r]);
            }
        }
}

// ---------------- aggregate v4: 8 edges/iter, 2 gathers in flight ----------------
__global__ __launch_bounds__(256)
void aggregate_v4(const unsigned short* __restrict__ h16, const int2* __restrict__ pay,
                  const int* __restrict__ offsets,
                  const float* __restrict__ dinv, const float* __restrict__ bias,
                  float* __restrict__ out, int n) {
    int wid  = (blockIdx.x * blockDim.x + threadIdx.x) >> 6;
    int lane = threadIdx.x & 63;
    if (wid >= n) return;
    const int g  = lane >> 4;          // edge subgroup 0..3
    const int f4 = (lane & 15) * 4;    // feature base

    float a0 = 0.f, a1 = 0.f, a2 = 0.f, a3 = 0.f;
    int beg = offsets[wid], end = offsets[wid + 1];
    int cnt = end - beg;
    int nq  = cnt >> 3;
    int e   = beg + g;
#pragma unroll 2
    for (int q = 0; q < nq; ++q, e += 8) {
        int2 p1 = pay[e];
        int2 p2 = pay[e + 4];
        float w1 = __int_as_float(p1.y);
        float w2 = __int_as_float(p2.y);
        ushort4 h1 = *(const ushort4*)(h16 + (size_t)p1.x * HID + f4);
        ushort4 h2 = *(const ushort4*)(h16 + (size_t)p2.x * HID + f4);
        a0 = fmaf(bf2f(h1.x), w1, a0); a1 = fmaf(bf2f(h1.y), w1, a1);
        a2 = fmaf(bf2f(h1.z), w1, a2); a3 = fmaf(bf2f(h1.w), w1, a3);
        a0 = fmaf(bf2f(h2.x), w2, a0); a1 = fmaf(bf2f(h2.y), w2, a1);
        a2 = fmaf(bf2f(h2.z), w2, a2); a3 = fmaf(bf2f(h2.w), w2, a3);
    }
    int rem  = cnt & 7;
    int base = beg + nq * 8;
    if (g < rem) {
        int2  pw  = pay[base + g];
        float wgt = __int_as_float(pw.y);
        ushort4 hv = *(const ushort4*)(h16 + (size_t)pw.x * HID + f4);
        a0 = fmaf(bf2f(hv.x), wgt, a0); a1 = fmaf(bf2f(hv.y), wgt, a1);
        a2 = fmaf(bf2f(hv.z), wgt, a2); a3 = fmaf(bf2f(hv.w), wgt, a3);
    }
    if (g + 4 < rem) {
        int2  pw  = pay[base + g + 4];
        float wgt = __int_as_float(pw.y);
        ushort4 hv = *(const ushort4*)(h16 + (size_t)pw.x * HID + f4);
        a0 = fmaf(bf2f(hv.x), wgt, a0); a1 = fmaf(bf2f(hv.y), wgt, a1);
        a2 = fmaf(bf2f(hv.z), wgt, a2); a3 = fmaf(bf2f(hv.w), wgt, a3);
    }
    if (g == 0) {   // self loop
        float di = dinv[wid];
        float w2 = di * di;
        ushort4 hv = *(const ushort4*)(h16 + (size_t)wid * HID + f4);
        a0 = fmaf(bf2f(hv.x), w2, a0); a1 = fmaf(bf2f(hv.y), w2, a1);
        a2 = fmaf(bf2f(hv.z), w2, a2); a3 = fmaf(bf2f(hv.w), w2, a3);
    }
    a0 += __shfl_xor(a0, 16); a0 += __shfl_xor(a0, 32);
    a1 += __shfl_xor(a1, 16); a1 += __shfl_xor(a1, 32);
    a2 += __shfl_xor(a2, 16); a2 += __shfl_xor(a2, 32);
    a3 += __shfl_xor(a3, 16); a3 += __shfl_xor(a3, 32);
    if (g == 0) {
        float4 bv = *(const float4*)&bias[f4];
        float4 o;
        o.x = fmaxf(a0 + bv.x, 0.f);
        o.y = fmaxf(a1 + bv.y, 0.f);
        o.z = fmaxf(a2 + bv.z, 0.f);
        o.w = fmaxf(a3 + bv.w, 0.f);
        *(float4*)&out[(size_t)wid * HID + f4] = o;
    }
}

// ---------------- fused MLP head via MFMA + butterfly log_softmax ----------------
__device__ __forceinline__ void split8(const float* v, short8v& h, short8v& l) {
    h = cvt8(v);
    float res[8];
#pragma unroll
    for (int j = 0; j < 8; ++j) res[j] = v[j] - bf2f((unsigned short)h[j]);
    l = cvt8(res);
}

__global__ __launch_bounds__(256)
void mlp_mfma(const float* __restrict__ y,
              const unsigned short* __restrict__ w1h, const unsigned short* __restrict__ w1l,
              const unsigned short* __restrict__ w2h, const unsigned short* __restrict__ w2l,
              const unsigned short* __restrict__ w3h, const unsigned short* __restrict__ w3l,
              const float* __restrict__ bf1, const float* __restrict__ bf2,
              const float* __restrict__ bf3,
              float* __restrict__ out, int M) {
    __shared__ float tbuf[4][32 * 64];
    const int t    = threadIdx.x;
    const int lane = t & 63;
    const int w    = t >> 6;
    const int m0   = blockIdx.x * 128 + w * 32;
    const int lrow = lane & 15;
    const int hi16 = lane >> 4;
    const int koff = hi16 * 8;
    float* tb = tbuf[w];

    float b1v[4], b2v[4];
#pragma unroll
    for (int nf = 0; nf < 4; ++nf) {
        b1v[nf] = bf1[nf * 16 + lrow];
        b2v[nf] = bf2[nf * 16 + lrow];
    }
    float b3v = (lrow < NCLS) ? bf3[lrow] : 0.f;

    short8v aH[2][2], aL[2][2];   // [mf][kt]
    {
        const float* a0 = y + (size_t)min(m0 + lrow,      M - 1) * 64;
        const float* a1 = y + (size_t)min(m0 + 16 + lrow, M - 1) * 64;
#pragma unroll
        for (int kt = 0; kt < 2; ++kt) {
            float v0[8], v1[8];
            __builtin_memcpy(v0, a0 + kt * 32 + koff, 32);
            __builtin_memcpy(v1, a1 + kt * 32 + koff, 32);
            split8(v0, aH[0][kt], aL[0][kt]);
            split8(v1, aH[1][kt], aL[1][kt]);
        }
    }

#pragma unroll
    for (int layer = 0; layer < 2; ++layer) {
        const unsigned short* wh = layer ? w2h : w1h;
        const unsigned short* wl = layer ? w2l : w1l;
        const float* bv = layer ? b2v : b1v;
        f32x4 acc[2][4];
#pragma unroll
        for (int i = 0; i < 2; ++i)
#pragma unroll
            for (int j = 0; j < 4; ++j) acc[i][j] = (f32x4){0.f, 0.f, 0.f, 0.f};
#pragma unroll
        for (int kt = 0; kt < 2; ++kt) {
            short8v bH[4], bL[4];
#pragma unroll
            for (int nf = 0; nf < 4; ++nf) {
                bH[nf] = *((const short8v*)wh + (kt * 4 + nf) * 64 + lane);
                bL[nf] = *((const short8v*)wl + (kt * 4 + nf) * 64 + lane);
            }
#pragma unroll
            for (int mf = 0; mf < 2; ++mf)
#pragma unroll
                for (int nf = 0; nf < 4; ++nf) {
                    acc[mf][nf] = __builtin_amdgcn_mfma_f32_16x16x32_bf16(aH[mf][kt], bH[nf], acc[mf][nf], 0, 0, 0);
                    acc[mf][nf] = __builtin_amdgcn_mfma_f32_16x16x32_bf16(aH[mf][kt], bL[nf], acc[mf][nf], 0, 0, 0);
                    acc[mf][nf] = __builtin_amdgcn_mfma_f32_16x16x32_bf16(aL[mf][kt], bH[nf], acc[mf][nf], 0, 0, 0);
                }
        }
#pragma unroll
        for (int mf = 0; mf < 2; ++mf)
#pragma unroll
            for (int nf = 0; nf < 4; ++nf)
#pragma unroll
                for (int r = 0; r < 4; ++r) {
                    int row = mf * 16 + hi16 * 4 + r;
                    int col = nf * 16 + lrow;
                    float v = fmaxf(acc[mf][nf][r] + bv[nf], 0.f);
                    *(float*)((char*)tb + ((((row << 6) + col) << 2) ^ ((row & 3) << 5))) = v;
                }
#pragma unroll
        for (int mf = 0; mf < 2; ++mf)
#pragma unroll
            for (int kt = 0; kt < 2; ++kt) {
                int row = mf * 16 + lrow;
                float v[8];
                __builtin_memcpy(v, (char*)tb + ((((row << 6) + kt * 32 + koff) << 2) ^ ((row & 3) << 5)), 32);
                split8(v, aH[mf][kt], aL[mf][kt]);
            }
    }

    f32x4 acc3[2];
    acc3[0] = (f32x4){0.f, 0.f, 0.f, 0.f};
    acc3[1] = (f32x4){0.f, 0.f, 0.f, 0.f};
#pragma unroll
    for (int kt = 0; kt < 2; ++kt) {
        short8v bH = *((const short8v*)w3h + kt * 64 + lane);
        short8v bL = *((const short8v*)w3l + kt * 64 + lane);
#pragma unroll
        for (int mf = 0; mf < 2; ++mf) {
            acc3[mf] = __builtin_amdgcn_mfma_f32_16x16x32_bf16(aH[mf][kt], bH, acc3[mf], 0, 0, 0);
            acc3[mf] = __builtin_amdgcn_mfma_f32_16x16x32_bf16(aH[mf][kt], bL, acc3[mf], 0, 0, 0);
            acc3[mf] = __builtin_amdgcn_mfma_f32_16x16x32_bf16(aL[mf][kt], bH, acc3[mf], 0, 0, 0);
        }
    }
#pragma unroll
    for (int mf = 0; mf < 2; ++mf)
#pragma unroll
        for (int r = 0; r < 4; ++r) {
            float z  = acc3[mf][r] + b3v;
            float zm = (lrow < NCLS) ? z : -1e30f;
            float m  = zm;
#pragma unroll
            for (int mask = 1; mask < 16; mask <<= 1)
                m = fmaxf(m, __shfl_xor(m, mask));
            float ev = (lrow < NCLS) ? expf(z - m) : 0.f;
            float ss = ev;
#pragma unroll
            for (int mask = 1; mask < 16; mask <<= 1)
                ss += __shfl_xor(ss, mask);
            float res = z - (m + logf(ss));
            int row = m0 + mf * 16 + hi16 * 4 + r;
            if (row < M && lrow < NCLS)
                out[(size_t)row * NCLS + lrow] = res;
        }
}

extern "C" void kernel_launch(void* const* d_in, const int* in_sizes, int n_in,
                              void* d_out, int out_size, void* d_ws, size_t ws_size,
                              hipStream_t stream) {
    const float* x   = (const float*)d_in[0];
    const int*   ei  = (const int*)d_in[1];
    const float* W1  = (const float*)d_in[2];
    const float* b1  = (const float*)d_in[3];
    const float* W2  = (const float*)d_in[4];
    const float* b2  = (const float*)d_in[5];
    const float* Wf1 = (const float*)d_in[6];
    const float* bf1 = (const float*)d_in[7];
    const float* Wf2 = (const float*)d_in[8];
    const float* bf2 = (const float*)d_in[9];
    const float* Wf3 = (const float*)d_in[10];
    const float* bf3 = (const float*)d_in[11];

    const int N = N_NODES;
    const int E = in_sizes[1] / 2;
    float* outp = (float*)d_out;

    char* p = (char*)d_ws;
    auto alloc = [&](size_t bytes) {
        char* q = p;
        p += (bytes + 255) & ~(size_t)255;
        return q;
    };
    int*            counts   = (int*)           alloc((size_t)N * 4);
    int*            offsets  = (int*)           alloc((size_t)(N + 1) * 4);
    int*            cursor   = (int*)           alloc((size_t)N * 4);
    int*            local_ex = (int*)           alloc((size_t)N * 4);
    int*            blocksum = (int*)           alloc((size_t)NBLK * 4);
    int*            blockoff = (int*)           alloc((size_t)NBLK * 4);
    float*          dinv     = (float*)         alloc((size_t)N * 4);
    int2*           pay      = (int2*)          alloc((size_t)E * 8);
    unsigned short* xf       = (unsigned short*)alloc((size_t)NBANDS * NKT1 * 64 * 8 * 2);  // 287.5 MB
    unsigned short* w1fh     = (unsigned short*)alloc((size_t)NKT1 * 4 * 64 * 8 * 2);
    unsigned short* w1fl     = (unsigned short*)alloc((size_t)NKT1 * 4 * 64 * 8 * 2);
    unsigned short* w2fh     = (unsigned short*)alloc((size_t)2 * 4 * 64 * 8 * 2);
    unsigned short* w2fl     = (unsigned short*)alloc((size_t)2 * 4 * 64 * 8 * 2);
    unsigned short* wf1h     = (unsigned short*)alloc((size_t)2 * 4 * 64 * 8 * 2);
    unsigned short* wf1l     = (unsigned short*)alloc((size_t)2 * 4 * 64 * 8 * 2);
    unsigned short* wf2h     = (unsigned short*)alloc((size_t)2 * 4 * 64 * 8 * 2);
    unsigned short* wf2l     = (unsigned short*)alloc((size_t)2 * 4 * 64 * 8 * 2);
    unsigned short* wf3h     = (unsigned short*)alloc((size_t)2 * 1 * 64 * 8 * 2);
    unsigned short* wf3l     = (unsigned short*)alloc((size_t)2 * 1 * 64 * 8 * 2);
    unsigned short* bufH16   = (unsigned short*)alloc((size_t)N * HID * 2);
    float*          bufF     = (float*)         alloc((size_t)N * HID * 4);

    const int* src = ei;
    const int* dst = ei + E;

    hipMemsetAsync(counts, 0, (size_t)N * 4, stream);
    int ge = (E + 255) / 256;     // 12500 hist/scatter blocks
    int GB = (N + 127) / 128;     // 782 gemm blocks

    // [x-convert | w-converts | hist]
    prep1<<<XCV_BLKS + WCV_BLKS + ge, 256, 0, stream>>>(
        x, xf, W1, w1fh, w1fl, W2, w2fh, w2fl,
        Wf1, wf1h, wf1l, Wf2, wf2h, wf2l, Wf3, wf3h, wf3l,
        dst, counts, E);
    scan_p1d<<<NBLK, SCAN_BLK, 0, stream>>>(counts, local_ex, blocksum, dinv, N);
    scan_p2<<<1, 128, 0, stream>>>(blocksum, blockoff, &offsets[N], NBLK);
    scan_p3<<<NBLK, SCAN_BLK, 0, stream>>>(local_ex, blockoff, offsets, cursor, N);

    // [gemm layer1 (frag-major A) | scatter]
    mega2<<<GB + ge, 256, 0, stream>>>(xf, w1fh, bufH16, N, GB,
                                       src, dst, dinv, cursor, pay, E);

    aggregate_v4<<<(N + 3) / 4, 256, 0, stream>>>(bufH16, pay, offsets, dinv, b1, bufF, N);
    gemm_hid_v3<<<(N + 127) / 128, 256, 0, stream>>>(bufF, w2fh, w2fl, bufH16, N);
    aggregate_v4<<<(N + 3) / 4, 256, 0, stream>>>(bufH16, pay, offsets, dinv, b2, bufF, N);
    mlp_mfma<<<(N + 127) / 128, 256, 0, stream>>>(bufF, wf1h, wf1l, wf2h, wf2l, wf3h, wf3l,
                                                  bf1, bf2, bf3, outp, N);
}

// Round 14
// 649.528 us; speedup vs baseline: 1.0460x; 1.0460x over previous
//
#include <hip/hip_runtime.h>
#include <hip/hip_bf16.h>

#define N_NODES 100000
#define N_FEAT  1433
#define NKT1    46       // k-tiles of 32 for K=1433->1472
#define HID     64
#define NCLS    7
#define NSPLIT  4
#define SCAN_BLK 1024
#define NBLK    ((N_NODES + SCAN_BLK - 1) / SCAN_BLK)   // 98

typedef __attribute__((ext_vector_type(8))) short short8v;
typedef __attribute__((ext_vector_type(4))) float f32x4;

__device__ __forceinline__ unsigned short f2bf(float v) {
    unsigned u = __float_as_uint(v);
    unsigned r = (u + 0x7FFFu + ((u >> 16) & 1u)) >> 16;   // RNE
    return (unsigned short)r;
}
__device__ __forceinline__ float bf2f(unsigned short h) {
    return __uint_as_float(((unsigned)h) << 16);
}

// packed f32x2 -> bf16x2 via v_cvt_pk_bf16_f32 (RNE)
__device__ __forceinline__ unsigned pk2(float a, float b) {
    union { __hip_bfloat162 h2; unsigned u; } cv;
    cv.h2 = __float22bfloat162_rn(make_float2(a, b));
    return cv.u;
}
__device__ __forceinline__ short8v cvt8(const float* v) {
    union { unsigned u[4]; short8v s; } r;
#pragma unroll
    for (int i = 0; i < 4; ++i) r.u[i] = pk2(v[2 * i], v[2 * i + 1]);
    return r.s;
}

// ---------------- W -> fragment-major bf16 hi/lo (device body) ----------------
__device__ __forceinline__
void convert_body(const float* __restrict__ W, int K, int ncols, int nfc, int tid, int total,
                  unsigned short* __restrict__ wfh, unsigned short* __restrict__ wfl) {
    if (tid >= total) return;
    int rem  = tid % (nfc * 64);
    int kt   = tid / (nfc * 64);
    int nf   = rem >> 6;
    int lane = rem & 63;
    int n  = nf * 16 + (lane & 15);
    int kb = kt * 32 + ((lane >> 4) << 3);
    short8v hi, lo;
#pragma unroll
    for (int j = 0; j < 8; ++j) {
        int k = kb + j;
        float v = (k < K && n < ncols) ? W[(size_t)k * ncols + n] : 0.f;
        unsigned short h = f2bf(v);
        hi[j] = (short)h;
        lo[j] = (short)f2bf(v - bf2f(h));
    }
    *(short8v*)(wfh + (size_t)tid * 8) = hi;
    *(short8v*)(wfl + (size_t)tid * 8) = lo;
}

// ---------------- prep1: [w-converts | hist] block-role-split ----------------
#define WCV_BLKS 53
__global__ __launch_bounds__(256)
void prep1(const float* __restrict__ W1,  unsigned short* w1fh, unsigned short* w1fl,
           const float* __restrict__ W2,  unsigned short* w2fh, unsigned short* w2fl,
           const float* __restrict__ Wf1, unsigned short* wf1h, unsigned short* wf1l,
           const float* __restrict__ Wf2, unsigned short* wf2h, unsigned short* wf2l,
           const float* __restrict__ Wf3, unsigned short* wf3h, unsigned short* wf3l,
           const int* __restrict__ dst, int* __restrict__ counts, int E) {
    int b = blockIdx.x;
    int t = threadIdx.x;
    if (b >= WCV_BLKS) {
        int e = (b - WCV_BLKS) * 256 + t;
        if (e < E) atomicAdd(&counts[dst[e]], 1);
        return;
    }
    if (b < 46)       convert_body(W1,  N_FEAT, 64, 4, b * 256 + t,        NKT1 * 4 * 64, w1fh, w1fl);
    else if (b < 48)  convert_body(W2,  64, 64,   4, (b - 46) * 256 + t,   2 * 4 * 64,    w2fh, w2fl);
    else if (b < 50)  convert_body(Wf1, 64, 64,   4, (b - 48) * 256 + t,   2 * 4 * 64,    wf1h, wf1l);
    else if (b < 52)  convert_body(Wf2, 64, 64,   4, (b - 50) * 256 + t,   2 * 4 * 64,    wf2h, wf2l);
    else              convert_body(Wf3, 64, NCLS, 1, (b - 52) * 256 + t,   2 * 1 * 64,    wf3h, wf3l);
}

// ---------------- 3-phase parallel exclusive scan (p1 fuses dinv) ----------------
__global__ __launch_bounds__(SCAN_BLK)
void scan_p1d(const int* __restrict__ counts, int* __restrict__ local_ex,
              int* __restrict__ blocksum, float* __restrict__ dinv, int n) {
    __shared__ int sh[SCAN_BLK];
    int t = threadIdx.x;
    int i = blockIdx.x * SCAN_BLK + t;
    int v = (i < n) ? counts[i] : 0;
    if (i < n) dinv[i] = rsqrtf((float)(v + 1));   // +1 = self loop
    sh[t] = v;
    __syncthreads();
    for (int off = 1; off < SCAN_BLK; off <<= 1) {
        int u = (t >= off) ? sh[t - off] : 0;
        __syncthreads();
        sh[t] += u;
        __syncthreads();
    }
    if (i < n) local_ex[i] = sh[t] - v;      // exclusive
    if (t == SCAN_BLK - 1) blocksum[blockIdx.x] = sh[t];
}

__global__ __launch_bounds__(128)
void scan_p2(int* __restrict__ blocksum, int* __restrict__ blockoff,
             int* __restrict__ offsets_last, int nb) {
    __shared__ int sh[128];
    int t = threadIdx.x;
    int v = (t < nb) ? blocksum[t] : 0;
    sh[t] = v;
    __syncthreads();
    for (int off = 1; off < 128; off <<= 1) {
        int u = (t >= off) ? sh[t - off] : 0;
        __syncthreads();
        sh[t] += u;
        __syncthreads();
    }
    if (t < nb) blockoff[t] = sh[t] - v;
    if (t == nb - 1) *offsets_last = sh[t];
}

__global__ __launch_bounds__(SCAN_BLK)
void scan_p3(const int* __restrict__ local_ex, const int* __restrict__ blockoff,
             int* __restrict__ offsets, int* __restrict__ cursor, int n) {
    int i = blockIdx.x * SCAN_BLK + threadIdx.x;
    if (i < n) {
        int v = local_ex[i] + blockoff[blockIdx.x];
        offsets[i] = v;
        cursor[i]  = v;
    }
}

// masked tail fragment load
__device__ __forceinline__ short8v load_frag_f32(const float* __restrict__ row, int kk) {
    float v[8];
#pragma unroll
    for (int j = 0; j < 8; ++j) v[j] = (kk + j < N_FEAT) ? row[kk + j] : 0.f;
    return cvt8(v);
}

// ---------------- GEMM1 body v12: v8 direct-load, K-split x4, f32 partial out ----------------
__device__ __forceinline__
void gemm_xw_body(int blk, int split, const float* __restrict__ X,
                  const unsigned short* __restrict__ wfh,
                  float* __restrict__ cpart, int M) {
    const int t    = threadIdx.x;
    const int lane = t & 63;
    const int w    = t >> 6;
    const int m0   = blk * 128 + w * 32;
    const int lrow = lane & 15;
    const int koff = (lane >> 4) * 8;

    f32x4 acc[2][4];
#pragma unroll
    for (int i = 0; i < 2; ++i)
#pragma unroll
        for (int j = 0; j < 4; ++j) acc[i][j] = (f32x4){0.f, 0.f, 0.f, 0.f};

    const float* a0 = X + (size_t)min(m0 + lrow,      M - 1) * N_FEAT;
    const float* a1 = X + (size_t)min(m0 + 16 + lrow, M - 1) * N_FEAT;
    const short8v* bh = (const short8v*)wfh + lane;   // + (kt*4+nf)*64

    const int k0 = split * 11;
    const int k1 = (split == 3) ? 44 : (k0 + 11);     // branch-free range

#pragma unroll 4
    for (int kt = k0; kt < k1; ++kt) {
        int kk = kt * 32 + koff;
        short8v aH[2], bH[4];
        float v0[8], v1[8];
        __builtin_memcpy(v0, a0 + kk, 32);
        __builtin_memcpy(v1, a1 + kk, 32);
        aH[0] = cvt8(v0);
        aH[1] = cvt8(v1);
#pragma unroll
        for (int nf = 0; nf < 4; ++nf)
            bH[nf] = bh[(kt * 4 + nf) * 64];
#pragma unroll
        for (int mf = 0; mf < 2; ++mf)
#pragma unroll
            for (int nf = 0; nf < 4; ++nf)
                acc[mf][nf] = __builtin_amdgcn_mfma_f32_16x16x32_bf16(aH[mf], bH[nf], acc[mf][nf], 0, 0, 0);
    }
    if (split == 3) {   // tail kt=44 (k 1408..1439, masked >= 1433)
        const int kt = 44;
        int kk = kt * 32 + koff;
        short8v aH[2], bH[4];
        aH[0] = load_frag_f32(a0, kk);
        aH[1] = load_frag_f32(a1, kk);
#pragma unroll
        for (int nf = 0; nf < 4; ++nf)
            bH[nf] = bh[(kt * 4 + nf) * 64];
#pragma unroll
        for (int mf = 0; mf < 2; ++mf)
#pragma unroll
            for (int nf = 0; nf < 4; ++nf)
                acc[mf][nf] = __builtin_amdgcn_mfma_f32_16x16x32_bf16(aH[mf], bH[nf], acc[mf][nf], 0, 0, 0);
    }
    // partial C (f32): col = lane&15, row = (lane>>4)*4 + reg
    float* cp = cpart + (size_t)split * M * 64;
#pragma unroll
    for (int mf = 0; mf < 2; ++mf)
#pragma unroll
        for (int r = 0; r < 4; ++r) {
            int row = m0 + mf * 16 + ((lane >> 4) << 2) + r;
            if (row < M) {
#pragma unroll
                for (int nf = 0; nf < 4; ++nf)
                    cp[(size_t)row * 64 + nf * 16 + lrow] = acc[mf][nf][r];
            }
        }
}

// ---------------- scatter body: single int2 payload (src, weight) ----------------
__device__ __forceinline__
void scatter_body(int blk, const int* __restrict__ src, const int* __restrict__ dst,
                  const float* __restrict__ dinv, int* __restrict__ cursor,
                  int2* __restrict__ pay, int E) {
    int e = blk * 256 + threadIdx.x;
    if (e >= E) return;
    int s = src[e], d = dst[e];
    int pos = atomicAdd(&cursor[d], 1);
    pay[pos] = make_int2(s, __float_as_int(dinv[s] * dinv[d]));
}

// ---------------- mega2: [K-split gemm | scatter] block-role-split (no LDS) ----------------
__global__ __launch_bounds__(256)
void mega2(const float* __restrict__ X, const unsigned short* __restrict__ w1fh,
           float* __restrict__ cpart, int M, int GB,
           const int* __restrict__ src, const int* __restrict__ dst,
           const float* __restrict__ dinv, int* __restrict__ cursor,
           int2* __restrict__ pay, int E) {
    int b = blockIdx.x;
    if (b < NSPLIT * GB) gemm_xw_body(b % GB, b / GB, X, w1fh, cpart, M);
    else                 scatter_body(b - NSPLIT * GB, src, dst, dinv, cursor, pay, E);
}

// ---------------- combine: sum 4 f32 partials -> bf16 ----------------
__global__ __launch_bounds__(256)
void combine_kernel(const float* __restrict__ cpart, unsigned short* __restrict__ H16, int M) {
    size_t idx = (size_t)blockIdx.x * 256 + threadIdx.x;   // over M*16 float4 groups
    size_t total = (size_t)M * 16;
    if (idx >= total) return;
    const float4* p = (const float4*)cpart;
    float4 v0 = p[idx];
    float4 v1 = p[idx + total];
    float4 v2 = p[idx + 2 * total];
    float4 v3 = p[idx + 3 * total];
    float s0 = (v0.x + v1.x) + (v2.x + v3.x);
    float s1 = (v0.y + v1.y) + (v2.y + v3.y);
    float s2 = (v0.z + v1.z) + (v2.z + v3.z);
    float s3 = (v0.w + v1.w) + (v2.w + v3.w);
    ushort4 o;
    o.x = f2bf(s0); o.y = f2bf(s1); o.z = f2bf(s2); o.w = f2bf(s3);
    ((ushort4*)H16)[idx] = o;
}

// ---------------- GEMM2 v3: [M,64] f32 @ [64,64], cvt_pk, frag-major W2 hi/lo ----------------
__global__ __launch_bounds__(256)
void gemm_hid_v3(const float* __restrict__ A,
                 const unsigned short* __restrict__ wfh,
                 const unsigned short* __restrict__ wfl,
                 unsigned short* __restrict__ H16, int M) {
    const int t    = threadIdx.x;
    const int lane = t & 63;
    const int w    = t >> 6;
    const int m0   = blockIdx.x * 128 + w * 32;
    const int lrow = lane & 15;
    const int koff = (lane >> 4) * 8;

    f32x4 acc[2][4];
#pragma unroll
    for (int i = 0; i < 2; ++i)
#pragma unroll
        for (int j = 0; j < 4; ++j) acc[i][j] = (f32x4){0.f, 0.f, 0.f, 0.f};

    const float* a0 = A + (size_t)min(m0 + lrow,      M - 1) * 64;
    const float* a1 = A + (size_t)min(m0 + 16 + lrow, M - 1) * 64;
    const short8v* bh = (const short8v*)wfh + lane;
    const short8v* bl = (const short8v*)wfl + lane;

#pragma unroll
    for (int kt = 0; kt < 2; ++kt) {
        int kk = kt * 32 + koff;
        short8v aH[2], bH[4], bL[4];
        float v0[8], v1[8];
        __builtin_memcpy(v0, a0 + kk, 32);
        __builtin_memcpy(v1, a1 + kk, 32);
        aH[0] = cvt8(v0);
        aH[1] = cvt8(v1);
#pragma unroll
        for (int nf = 0; nf < 4; ++nf) {
            bH[nf] = bh[(kt * 4 + nf) * 64];
            bL[nf] = bl[(kt * 4 + nf) * 64];
        }
#pragma unroll
        for (int mf = 0; mf < 2; ++mf)
#pragma unroll
            for (int nf = 0; nf < 4; ++nf) {
                acc[mf][nf] = __builtin_amdgcn_mfma_f32_16x16x32_bf16(aH[mf], bH[nf], acc[mf][nf], 0, 0, 0);
                acc[mf][nf] = __builtin_amdgcn_mfma_f32_16x16x32_bf16(aH[mf], bL[nf], acc[mf][nf], 0, 0, 0);
            }
    }
#pragma unroll
    for (int mf = 0; mf < 2; ++mf)
#pragma unroll
        for (int r = 0; r < 4; ++r) {
            int row = m0 + mf * 16 + ((lane >> 4) << 2) + r;
            if (row < M) {
#pragma unroll
                for (int nf = 0; nf < 4; ++nf)
                    H16[(size_t)row * 64 + nf * 16 + lrow] = f2bf(acc[mf][nf][r]);
            }
        }
}

// ---------------- aggregate v4: 8 edges/iter, 2 gathers in flight ----------------
__global__ __launch_bounds__(256)
void aggregate_v4(const unsigned short* __restrict__ h16, const int2* __restrict__ pay,
                  const int* __restrict__ offsets,
                  const float* __restrict__ dinv, const float* __restrict__ bias,
                  float* __restrict__ out, int n) {
    int wid  = (blockIdx.x * blockDim.x + threadIdx.x) >> 6;
    int lane = threadIdx.x & 63;
    if (wid >= n) return;
    const int g  = lane >> 4;          // edge subgroup 0..3
    const int f4 = (lane & 15) * 4;    // feature base

    float a0 = 0.f, a1 = 0.f, a2 = 0.f, a3 = 0.f;
    int beg = offsets[wid], end = offsets[wid + 1];
    int cnt = end - beg;
    int nq  = cnt >> 3;
    int e   = beg + g;
#pragma unroll 2
    for (int q = 0; q < nq; ++q, e += 8) {
        int2 p1 = pay[e];
        int2 p2 = pay[e + 4];
        float w1 = __int_as_float(p1.y);
        float w2 = __int_as_float(p2.y);
        ushort4 h1 = *(const ushort4*)(h16 + (size_t)p1.x * HID + f4);
        ushort4 h2 = *(const ushort4*)(h16 + (size_t)p2.x * HID + f4);
        a0 = fmaf(bf2f(h1.x), w1, a0); a1 = fmaf(bf2f(h1.y), w1, a1);
        a2 = fmaf(bf2f(h1.z), w1, a2); a3 = fmaf(bf2f(h1.w), w1, a3);
        a0 = fmaf(bf2f(h2.x), w2, a0); a1 = fmaf(bf2f(h2.y), w2, a1);
        a2 = fmaf(bf2f(h2.z), w2, a2); a3 = fmaf(bf2f(h2.w), w2, a3);
    }
    int rem  = cnt & 7;
    int base = beg + nq * 8;
    if (g < rem) {
        int2  pw  = pay[base + g];
        float wgt = __int_as_float(pw.y);
        ushort4 hv = *(const ushort4*)(h16 + (size_t)pw.x * HID + f4);
        a0 = fmaf(bf2f(hv.x), wgt, a0); a1 = fmaf(bf2f(hv.y), wgt, a1);
        a2 = fmaf(bf2f(hv.z), wgt, a2); a3 = fmaf(bf2f(hv.w), wgt, a3);
    }
    if (g + 4 < rem) {
        int2  pw  = pay[base + g + 4];
        float wgt = __int_as_float(pw.y);
        ushort4 hv = *(const ushort4*)(h16 + (size_t)pw.x * HID + f4);
        a0 = fmaf(bf2f(hv.x), wgt, a0); a1 = fmaf(bf2f(hv.y), wgt, a1);
        a2 = fmaf(bf2f(hv.z), wgt, a2); a3 = fmaf(bf2f(hv.w), wgt, a3);
    }
    if (g == 0) {   // self loop
        float di = dinv[wid];
        float w2 = di * di;
        ushort4 hv = *(const ushort4*)(h16 + (size_t)wid * HID + f4);
        a0 = fmaf(bf2f(hv.x), w2, a0); a1 = fmaf(bf2f(hv.y), w2, a1);
        a2 = fmaf(bf2f(hv.z), w2, a2); a3 = fmaf(bf2f(hv.w), w2, a3);
    }
    a0 += __shfl_xor(a0, 16); a0 += __shfl_xor(a0, 32);
    a1 += __shfl_xor(a1, 16); a1 += __shfl_xor(a1, 32);
    a2 += __shfl_xor(a2, 16); a2 += __shfl_xor(a2, 32);
    a3 += __shfl_xor(a3, 16); a3 += __shfl_xor(a3, 32);
    if (g == 0) {
        float4 bv = *(const float4*)&bias[f4];
        float4 o;
        o.x = fmaxf(a0 + bv.x, 0.f);
        o.y = fmaxf(a1 + bv.y, 0.f);
        o.z = fmaxf(a2 + bv.z, 0.f);
        o.w = fmaxf(a3 + bv.w, 0.f);
        *(float4*)&out[(size_t)wid * HID + f4] = o;
    }
}

// ---------------- fused MLP head via MFMA + butterfly log_softmax ----------------
__device__ __forceinline__ void split8(const float* v, short8v& h, short8v& l) {
    h = cvt8(v);
    float res[8];
#pragma unroll
    for (int j = 0; j < 8; ++j) res[j] = v[j] - bf2f((unsigned short)h[j]);
    l = cvt8(res);
}

__global__ __launch_bounds__(256)
void mlp_mfma(const float* __restrict__ y,
              const unsigned short* __restrict__ w1h, const unsigned short* __restrict__ w1l,
              const unsigned short* __restrict__ w2h, const unsigned short* __restrict__ w2l,
              const unsigned short* __restrict__ w3h, const unsigned short* __restrict__ w3l,
              const float* __restrict__ bf1, const float* __restrict__ bf2,
              const float* __restrict__ bf3,
              float* __restrict__ out, int M) {
    __shared__ float tbuf[4][32 * 64];
    const int t    = threadIdx.x;
    const int lane = t & 63;
    const int w    = t >> 6;
    const int m0   = blockIdx.x * 128 + w * 32;
    const int lrow = lane & 15;
    const int hi16 = lane >> 4;
    const int koff = hi16 * 8;
    float* tb = tbuf[w];

    float b1v[4], b2v[4];
#pragma unroll
    for (int nf = 0; nf < 4; ++nf) {
        b1v[nf] = bf1[nf * 16 + lrow];
        b2v[nf] = bf2[nf * 16 + lrow];
    }
    float b3v = (lrow < NCLS) ? bf3[lrow] : 0.f;

    short8v aH[2][2], aL[2][2];   // [mf][kt]
    {
        const float* a0 = y + (size_t)min(m0 + lrow,      M - 1) * 64;
        const float* a1 = y + (size_t)min(m0 + 16 + lrow, M - 1) * 64;
#pragma unroll
        for (int kt = 0; kt < 2; ++kt) {
            float v0[8], v1[8];
            __builtin_memcpy(v0, a0 + kt * 32 + koff, 32);
            __builtin_memcpy(v1, a1 + kt * 32 + koff, 32);
            split8(v0, aH[0][kt], aL[0][kt]);
            split8(v1, aH[1][kt], aL[1][kt]);
        }
    }

#pragma unroll
    for (int layer = 0; layer < 2; ++layer) {
        const unsigned short* wh = layer ? w2h : w1h;
        const unsigned short* wl = layer ? w2l : w1l;
        const float* bv = layer ? b2v : b1v;
        f32x4 acc[2][4];
#pragma unroll
        for (int i = 0; i < 2; ++i)
#pragma unroll
            for (int j = 0; j < 4; ++j) acc[i][j] = (f32x4){0.f, 0.f, 0.f, 0.f};
#pragma unroll
        for (int kt = 0; kt < 2; ++kt) {
            short8v bH[4], bL[4];
#pragma unroll
            for (int nf = 0; nf < 4; ++nf) {
                bH[nf] = *((const short8v*)wh + (kt * 4 + nf) * 64 + lane);
                bL[nf] = *((const short8v*)wl + (kt * 4 + nf) * 64 + lane);
            }
#pragma unroll
            for (int mf = 0; mf < 2; ++mf)
#pragma unroll
                for (int nf = 0; nf < 4; ++nf) {
                    acc[mf][nf] = __builtin_amdgcn_mfma_f32_16x16x32_bf16(aH[mf][kt], bH[nf], acc[mf][nf], 0, 0, 0);
                    acc[mf][nf] = __builtin_amdgcn_mfma_f32_16x16x32_bf16(aH[mf][kt], bL[nf], acc[mf][nf], 0, 0, 0);
                    acc[mf][nf] = __builtin_amdgcn_mfma_f32_16x16x32_bf16(aL[mf][kt], bH[nf], acc[mf][nf], 0, 0, 0);
                }
        }
#pragma unroll
        for (int mf = 0; mf < 2; ++mf)
#pragma unroll
            for (int nf = 0; nf < 4; ++nf)
#pragma unroll
                for (int r = 0; r < 4; ++r) {
                    int row = mf * 16 + hi16 * 4 + r;
                    int col = nf * 16 + lrow;
                    float v = fmaxf(acc[mf][nf][r] + bv[nf], 0.f);
                    *(float*)((char*)tb + ((((row << 6) + col) << 2) ^ ((row & 3) << 5))) = v;
                }
#pragma unroll
        for (int mf = 0; mf < 2; ++mf)
#pragma unroll
            for (int kt = 0; kt < 2; ++kt) {
                int row = mf * 16 + lrow;
                float v[8];
                __builtin_memcpy(v, (char*)tb + ((((row << 6) + kt * 32 + koff) << 2) ^ ((row & 3) << 5)), 32);
                split8(v, aH[mf][kt], aL[mf][kt]);
            }
    }

    f32x4 acc3[2];
    acc3[0] = (f32x4){0.f, 0.f, 0.f, 0.f};
    acc3[1] = (f32x4){0.f, 0.f, 0.f, 0.f};
#pragma unroll
    for (int kt = 0; kt < 2; ++kt) {
        short8v bH = *((const short8v*)w3h + kt * 64 + lane);
        short8v bL = *((const short8v*)w3l + kt * 64 + lane);
#pragma unroll
        for (int mf = 0; mf < 2; ++mf) {
            acc3[mf] = __builtin_amdgcn_mfma_f32_16x16x32_bf16(aH[mf][kt], bH, acc3[mf], 0, 0, 0);
            acc3[mf] = __builtin_amdgcn_mfma_f32_16x16x32_bf16(aH[mf][kt], bL, acc3[mf], 0, 0, 0);
            acc3[mf] = __builtin_amdgcn_mfma_f32_16x16x32_bf16(aL[mf][kt], bH, acc3[mf], 0, 0, 0);
        }
    }
#pragma unroll
    for (int mf = 0; mf < 2; ++mf)
#pragma unroll
        for (int r = 0; r < 4; ++r) {
            float z  = acc3[mf][r] + b3v;
            float zm = (lrow < NCLS) ? z : -1e30f;
            float m  = zm;
#pragma unroll
            for (int mask = 1; mask < 16; mask <<= 1)
                m = fmaxf(m, __shfl_xor(m, mask));
            float ev = (lrow < NCLS) ? expf(z - m) : 0.f;
            float ss = ev;
#pragma unroll
            for (int mask = 1; mask < 16; mask <<= 1)
                ss += __shfl_xor(ss, mask);
            float res = z - (m + logf(ss));
            int row = m0 + mf * 16 + hi16 * 4 + r;
            if (row < M && lrow < NCLS)
                out[(size_t)row * NCLS + lrow] = res;
        }
}

extern "C" void kernel_launch(void* const* d_in, const int* in_sizes, int n_in,
                              void* d_out, int out_size, void* d_ws, size_t ws_size,
                              hipStream_t stream) {
    const float* x   = (const float*)d_in[0];
    const int*   ei  = (const int*)d_in[1];
    const float* W1  = (const float*)d_in[2];
    const float* b1  = (const float*)d_in[3];
    const float* W2  = (const float*)d_in[4];
    const float* b2  = (const float*)d_in[5];
    const float* Wf1 = (const float*)d_in[6];
    const float* bf1 = (const float*)d_in[7];
    const float* Wf2 = (const float*)d_in[8];
    const float* bf2 = (const float*)d_in[9];
    const float* Wf3 = (const float*)d_in[10];
    const float* bf3 = (const float*)d_in[11];

    const int N = N_NODES;
    const int E = in_sizes[1] / 2;
    float* outp = (float*)d_out;

    char* p = (char*)d_ws;
    auto alloc = [&](size_t bytes) {
        char* q = p;
        p += (bytes + 255) & ~(size_t)255;
        return q;
    };
    int*            counts   = (int*)           alloc((size_t)N * 4);
    int*            offsets  = (int*)           alloc((size_t)(N + 1) * 4);
    int*            cursor   = (int*)           alloc((size_t)N * 4);
    int*            local_ex = (int*)           alloc((size_t)N * 4);
    int*            blocksum = (int*)           alloc((size_t)NBLK * 4);
    int*            blockoff = (int*)           alloc((size_t)NBLK * 4);
    float*          dinv     = (float*)         alloc((size_t)N * 4);
    int2*           pay      = (int2*)          alloc((size_t)E * 8);
    float*          cpart    = (float*)         alloc((size_t)NSPLIT * N * 64 * 4);   // 102.4 MB
    unsigned short* w1fh     = (unsigned short*)alloc((size_t)NKT1 * 4 * 64 * 8 * 2);
    unsigned short* w1fl     = (unsigned short*)alloc((size_t)NKT1 * 4 * 64 * 8 * 2);
    unsigned short* w2fh     = (unsigned short*)alloc((size_t)2 * 4 * 64 * 8 * 2);
    unsigned short* w2fl     = (unsigned short*)alloc((size_t)2 * 4 * 64 * 8 * 2);
    unsigned short* wf1h     = (unsigned short*)alloc((size_t)2 * 4 * 64 * 8 * 2);
    unsigned short* wf1l     = (unsigned short*)alloc((size_t)2 * 4 * 64 * 8 * 2);
    unsigned short* wf2h     = (unsigned short*)alloc((size_t)2 * 4 * 64 * 8 * 2);
    unsigned short* wf2l     = (unsigned short*)alloc((size_t)2 * 4 * 64 * 8 * 2);
    unsigned short* wf3h     = (unsigned short*)alloc((size_t)2 * 1 * 64 * 8 * 2);
    unsigned short* wf3l     = (unsigned short*)alloc((size_t)2 * 1 * 64 * 8 * 2);
    unsigned short* bufH16   = (unsigned short*)alloc((size_t)N * HID * 2);
    float*          bufF     = (float*)         alloc((size_t)N * HID * 4);

    const int* src = ei;
    const int* dst = ei + E;

    hipMemsetAsync(counts, 0, (size_t)N * 4, stream);
    int ge = (E + 255) / 256;     // 12500 hist/scatter blocks
    int GB = (N + 127) / 128;     // 782 gemm tile-blocks (x4 splits)

    // [w-converts | hist]
    prep1<<<WCV_BLKS + ge, 256, 0, stream>>>(W1, w1fh, w1fl, W2, w2fh, w2fl,
                                             Wf1, wf1h, wf1l, Wf2, wf2h, wf2l,
                                             Wf3, wf3h, wf3l, dst, counts, E);
    scan_p1d<<<NBLK, SCAN_BLK, 0, stream>>>(counts, local_ex, blocksum, dinv, N);
    scan_p2<<<1, 128, 0, stream>>>(blocksum, blockoff, &offsets[N], NBLK);
    scan_p3<<<NBLK, SCAN_BLK, 0, stream>>>(local_ex, blockoff, offsets, cursor, N);

    // [K-split gemm layer1 | scatter]
    mega2<<<NSPLIT * GB + ge, 256, 0, stream>>>(x, w1fh, cpart, N, GB,
                                                src, dst, dinv, cursor, pay, E);
    combine_kernel<<<(N * 16 + 255) / 256, 256, 0, stream>>>(cpart, bufH16, N);

    aggregate_v4<<<(N + 3) / 4, 256, 0, stream>>>(bufH16, pay, offsets, dinv, b1, bufF, N);
    gemm_hid_v3<<<(N + 127) / 128, 256, 0, stream>>>(bufF, w2fh, w2fl, bufH16, N);
    aggregate_v4<<<(N + 3) / 4, 256, 0, stream>>>(bufH16, pay, offsets, dinv, b2, bufF, N);
    mlp_mfma<<<(N + 127) / 128, 256, 0, stream>>>(bufF, wf1h, wf1l, wf2h, wf2l, wf3h, wf3l,
                                                  bf1, bf2, bf3, outp, N);
}

// Round 15
// 606.968 us; speedup vs baseline: 1.1194x; 1.0701x over previous
//
#include <hip/hip_runtime.h>
#include <hip/hip_bf16.h>

#define N_NODES 100000
#define N_FEAT  1433
#define NKT1    46       // k-tiles of 32 for K=1433->1472
#define HID     64
#define NCLS    7
#define SCAN_BLK 1024
#define NBLK    ((N_NODES + SCAN_BLK - 1) / SCAN_BLK)   // 98

typedef __attribute__((ext_vector_type(8))) short short8v;
typedef __attribute__((ext_vector_type(4))) float f32x4;

__device__ __forceinline__ unsigned short f2bf(float v) {
    unsigned u = __float_as_uint(v);
    unsigned r = (u + 0x7FFFu + ((u >> 16) & 1u)) >> 16;   // RNE
    return (unsigned short)r;
}
__device__ __forceinline__ float bf2f(unsigned short h) {
    return __uint_as_float(((unsigned)h) << 16);
}

// packed f32x2 -> bf16x2 via v_cvt_pk_bf16_f32 (RNE)
__device__ __forceinline__ unsigned pk2(float a, float b) {
    union { __hip_bfloat162 h2; unsigned u; } cv;
    cv.h2 = __float22bfloat162_rn(make_float2(a, b));
    return cv.u;
}
__device__ __forceinline__ short8v cvt8(const float* v) {
    union { unsigned u[4]; short8v s; } r;
#pragma unroll
    for (int i = 0; i < 4; ++i) r.u[i] = pk2(v[2 * i], v[2 * i + 1]);
    return r.s;
}

// async global->LDS, 4 bytes/lane, LDS dest = uniform base + lane*4
__device__ __forceinline__ void gl_lds4(const float* g, char* l) {
    __builtin_amdgcn_global_load_lds(
        (const __attribute__((address_space(1))) unsigned*)g,
        (__attribute__((address_space(3))) unsigned*)l, 4, 0, 0);
}

// ---------------- W -> fragment-major bf16 hi/lo (device body) ----------------
__device__ __forceinline__
void convert_body(const float* __restrict__ W, int K, int ncols, int nfc, int tid, int total,
                  unsigned short* __restrict__ wfh, unsigned short* __restrict__ wfl) {
    if (tid >= total) return;
    int rem  = tid % (nfc * 64);
    int kt   = tid / (nfc * 64);
    int nf   = rem >> 6;
    int lane = rem & 63;
    int n  = nf * 16 + (lane & 15);
    int kb = kt * 32 + ((lane >> 4) << 3);
    short8v hi, lo;
#pragma unroll
    for (int j = 0; j < 8; ++j) {
        int k = kb + j;
        float v = (k < K && n < ncols) ? W[(size_t)k * ncols + n] : 0.f;
        unsigned short h = f2bf(v);
        hi[j] = (short)h;
        lo[j] = (short)f2bf(v - bf2f(h));
    }
    *(short8v*)(wfh + (size_t)tid * 8) = hi;
    *(short8v*)(wfl + (size_t)tid * 8) = lo;
}

// ---------------- prep1: [w-converts | hist] block-role-split ----------------
#define WCV_BLKS 53
__global__ __launch_bounds__(256)
void prep1(const float* __restrict__ W1,  unsigned short* w1fh, unsigned short* w1fl,
           const float* __restrict__ W2,  unsigned short* w2fh, unsigned short* w2fl,
           const float* __restrict__ Wf1, unsigned short* wf1h, unsigned short* wf1l,
           const float* __restrict__ Wf2, unsigned short* wf2h, unsigned short* wf2l,
           const float* __restrict__ Wf3, unsigned short* wf3h, unsigned short* wf3l,
           const int* __restrict__ dst, int* __restrict__ counts, int E) {
    int b = blockIdx.x;
    int t = threadIdx.x;
    if (b >= WCV_BLKS) {
        int e = (b - WCV_BLKS) * 256 + t;
        if (e < E) atomicAdd(&counts[dst[e]], 1);
        return;
    }
    if (b < 46)       convert_body(W1,  N_FEAT, 64, 4, b * 256 + t,        NKT1 * 4 * 64, w1fh, w1fl);
    else if (b < 48)  convert_body(W2,  64, 64,   4, (b - 46) * 256 + t,   2 * 4 * 64,    w2fh, w2fl);
    else if (b < 50)  convert_body(Wf1, 64, 64,   4, (b - 48) * 256 + t,   2 * 4 * 64,    wf1h, wf1l);
    else if (b < 52)  convert_body(Wf2, 64, 64,   4, (b - 50) * 256 + t,   2 * 4 * 64,    wf2h, wf2l);
    else              convert_body(Wf3, 64, NCLS, 1, (b - 52) * 256 + t,   2 * 1 * 64,    wf3h, wf3l);
}

// ---------------- 3-phase parallel exclusive scan (p1 fuses dinv) ----------------
__global__ __launch_bounds__(SCAN_BLK)
void scan_p1d(const int* __restrict__ counts, int* __restrict__ local_ex,
              int* __restrict__ blocksum, float* __restrict__ dinv, int n) {
    __shared__ int sh[SCAN_BLK];
    int t = threadIdx.x;
    int i = blockIdx.x * SCAN_BLK + t;
    int v = (i < n) ? counts[i] : 0;
    if (i < n) dinv[i] = rsqrtf((float)(v + 1));   // +1 = self loop
    sh[t] = v;
    __syncthreads();
    for (int off = 1; off < SCAN_BLK; off <<= 1) {
        int u = (t >= off) ? sh[t - off] : 0;
        __syncthreads();
        sh[t] += u;
        __syncthreads();
    }
    if (i < n) local_ex[i] = sh[t] - v;      // exclusive
    if (t == SCAN_BLK - 1) blocksum[blockIdx.x] = sh[t];
}

__global__ __launch_bounds__(128)
void scan_p2(int* __restrict__ blocksum, int* __restrict__ blockoff,
             int* __restrict__ offsets_last, int nb) {
    __shared__ int sh[128];
    int t = threadIdx.x;
    int v = (t < nb) ? blocksum[t] : 0;
    sh[t] = v;
    __syncthreads();
    for (int off = 1; off < 128; off <<= 1) {
        int u = (t >= off) ? sh[t - off] : 0;
        __syncthreads();
        sh[t] += u;
        __syncthreads();
    }
    if (t < nb) blockoff[t] = sh[t] - v;
    if (t == nb - 1) *offsets_last = sh[t];
}

__global__ __launch_bounds__(SCAN_BLK)
void scan_p3(const int* __restrict__ local_ex, const int* __restrict__ blockoff,
             int* __restrict__ offsets, int* __restrict__ cursor, int n) {
    int i = blockIdx.x * SCAN_BLK + threadIdx.x;
    if (i < n) {
        int v = local_ex[i] + blockoff[blockIdx.x];
        offsets[i] = v;
        cursor[i]  = v;
    }
}

// masked tail fragment load
__device__ __forceinline__ short8v load_frag_f32(const float* __restrict__ row, int kk) {
    float v[8];
#pragma unroll
    for (int j = 0; j < 8; ++j) v[j] = (kk + j < N_FEAT) ? row[kk + j] : 0.f;
    return cvt8(v);
}

// ---------------- GEMM1 body v13: wave-private double-buffered gl_lds, counted vmcnt ----------------
// Wave = 16 rows. Per K-step (64 cols): 16 gl_lds (256B contiguous each, swizzled source)
// + 8 B-loads into alternating reg set = 24 vmem ops. s_waitcnt vmcnt(24) retires the
// PREVIOUS batch while the new one stays in flight (T4 counted-vmcnt, no barriers needed).
__device__ __forceinline__
void gemm_xw_body(int blk, const float* __restrict__ X,
                  const unsigned short* __restrict__ wfh,
                  unsigned short* __restrict__ H16, int M, char* smem) {
    const int t    = threadIdx.x;
    const int lane = t & 63;
    const int w    = t >> 6;
    const int m0   = blk * 64 + w * 16;
    const int lrow = lane & 15;
    char* sw = smem + w * 8192;          // 2 buffers x 4KB

    f32x4 acc[4];
#pragma unroll
    for (int j = 0; j < 4; ++j) acc[j] = (f32x4){0.f, 0.f, 0.f, 0.f};

    const short8v* bh = (const short8v*)wfh + lane;
    short8v breg[2][2][4];               // [set][ktHalf][nf] — all indices compile-time

    // swizzled per-row global base pointers (involution: col ^= (row&7)*4 elements)
    const float* rb[16];
#pragma unroll
    for (int i = 0; i < 16; ++i)
        rb[i] = X + (size_t)min(m0 + i, M - 1) * N_FEAT + (lane ^ ((i & 7) << 2));

    auto issue = [&](int s, int set) {
        char* dst = sw + set * 4096;
#pragma unroll
        for (int i = 0; i < 16; ++i)
            gl_lds4(rb[i] + s * 64, dst + i * 256);
#pragma unroll
        for (int h = 0; h < 2; ++h)
#pragma unroll
            for (int nf = 0; nf < 4; ++nf)
                breg[set][h][nf] = bh[((2 * s + h) * 4 + nf) * 64];
    };
    auto compute = [&](int set) {
        char* buf = sw + set * 4096;
#pragma unroll
        for (int h = 0; h < 2; ++h) {
            float v[8];
            int u0 = h * 128 + ((lane >> 4) << 5);
            int sb = lrow * 256;
            int sx = (lrow & 7) << 4;
            __builtin_memcpy(v,     buf + sb + ((u0     ) ^ sx), 16);
            __builtin_memcpy(v + 4, buf + sb + ((u0 + 16) ^ sx), 16);
            short8v aH = cvt8(v);
#pragma unroll
            for (int nf = 0; nf < 4; ++nf)
                acc[nf] = __builtin_amdgcn_mfma_f32_16x16x32_bf16(aH, breg[set][h][nf], acc[nf], 0, 0, 0);
        }
    };

    issue(0, 0);                          // prologue: batch 0 in flight
#pragma unroll 2
    for (int s = 0; s < 21; ++s) {        // steps 0..20 (kt 0..41)
        issue(s + 1, (s + 1) & 1);        // batch s+1 in flight (24 ops)
        __builtin_amdgcn_sched_barrier(0);
        asm volatile("s_waitcnt vmcnt(24)" ::: "memory");   // batch s fully landed
        __builtin_amdgcn_sched_barrier(0);
        compute(s & 1);
    }
    asm volatile("s_waitcnt vmcnt(0)" ::: "memory");        // final batch (s=21)
    __builtin_amdgcn_sched_barrier(0);
    compute(1);                           // step 21 (kt 42,43), set = 21&1

    {   // tail kt=44 (cols 1408..1439, masked >= 1433) — direct from global
        const int kt = 44;
        const int koff = (lane >> 4) * 8;
        const float* a0 = X + (size_t)min(m0 + lrow, M - 1) * N_FEAT;
        short8v aH = load_frag_f32(a0, kt * 32 + koff);
#pragma unroll
        for (int nf = 0; nf < 4; ++nf) {
            short8v bT = bh[(kt * 4 + nf) * 64];
            acc[nf] = __builtin_amdgcn_mfma_f32_16x16x32_bf16(aH, bT, acc[nf], 0, 0, 0);
        }
    }
    // C: col = lane&15, row = (lane>>4)*4 + reg
#pragma unroll
    for (int r = 0; r < 4; ++r) {
        int row = m0 + ((lane >> 4) << 2) + r;
        if (row < M) {
#pragma unroll
            for (int nf = 0; nf < 4; ++nf)
                H16[(size_t)row * 64 + nf * 16 + lrow] = f2bf(acc[nf][r]);
        }
    }
}

// ---------------- scatter body: single int2 payload (src, weight) ----------------
__device__ __forceinline__
void scatter_body(int blk, const int* __restrict__ src, const int* __restrict__ dst,
                  const float* __restrict__ dinv, int* __restrict__ cursor,
                  int2* __restrict__ pay, int E) {
    int e = blk * 256 + threadIdx.x;
    if (e >= E) return;
    int s = src[e], d = dst[e];
    int pos = atomicAdd(&cursor[d], 1);
    pay[pos] = make_int2(s, __float_as_int(dinv[s] * dinv[d]));
}

// ---------------- mega2: [gemm | scatter] block-role-split (32KB LDS) ----------------
__global__ __launch_bounds__(256)
void mega2(const float* __restrict__ X, const unsigned short* __restrict__ w1fh,
           unsigned short* __restrict__ H16, int M, int GB,
           const int* __restrict__ src, const int* __restrict__ dst,
           const float* __restrict__ dinv, int* __restrict__ cursor,
           int2* __restrict__ pay, int E) {
    __shared__ __align__(16) char smem[32768];
    int b = blockIdx.x;
    if (b < GB) gemm_xw_body(b, X, w1fh, H16, M, smem);
    else        scatter_body(b - GB, src, dst, dinv, cursor, pay, E);
}

// ---------------- GEMM2 v3: [M,64] f32 @ [64,64], cvt_pk, frag-major W2 hi/lo ----------------
__global__ __launch_bounds__(256)
void gemm_hid_v3(const float* __restrict__ A,
                 const unsigned short* __restrict__ wfh,
                 const unsigned short* __restrict__ wfl,
                 unsigned short* __restrict__ H16, int M) {
    const int t    = threadIdx.x;
    const int lane = t & 63;
    const int w    = t >> 6;
    const int m0   = blockIdx.x * 128 + w * 32;
    const int lrow = lane & 15;
    const int koff = (lane >> 4) * 8;

    f32x4 acc[2][4];
#pragma unroll
    for (int i = 0; i < 2; ++i)
#pragma unroll
        for (int j = 0; j < 4; ++j) acc[i][j] = (f32x4){0.f, 0.f, 0.f, 0.f};

    const float* a0 = A + (size_t)min(m0 + lrow,      M - 1) * 64;
    const float* a1 = A + (size_t)min(m0 + 16 + lrow, M - 1) * 64;
    const short8v* bh = (const short8v*)wfh + lane;
    const short8v* bl = (const short8v*)wfl + lane;

#pragma unroll
    for (int kt = 0; kt < 2; ++kt) {
        int kk = kt * 32 + koff;
        short8v aH[2], bH[4], bL[4];
        float v0[8], v1[8];
        __builtin_memcpy(v0, a0 + kk, 32);
        __builtin_memcpy(v1, a1 + kk, 32);
        aH[0] = cvt8(v0);
        aH[1] = cvt8(v1);
#pragma unroll
        for (int nf = 0; nf < 4; ++nf) {
            bH[nf] = bh[(kt * 4 + nf) * 64];
            bL[nf] = bl[(kt * 4 + nf) * 64];
        }
#pragma unroll
        for (int mf = 0; mf < 2; ++mf)
#pragma unroll
            for (int nf = 0; nf < 4; ++nf) {
                acc[mf][nf] = __builtin_amdgcn_mfma_f32_16x16x32_bf16(aH[mf], bH[nf], acc[mf][nf], 0, 0, 0);
                acc[mf][nf] = __builtin_amdgcn_mfma_f32_16x16x32_bf16(aH[mf], bL[nf], acc[mf][nf], 0, 0, 0);
            }
    }
#pragma unroll
    for (int mf = 0; mf < 2; ++mf)
#pragma unroll
        for (int r = 0; r < 4; ++r) {
            int row = m0 + mf * 16 + ((lane >> 4) << 2) + r;
            if (row < M) {
#pragma unroll
                for (int nf = 0; nf < 4; ++nf)
                    H16[(size_t)row * 64 + nf * 16 + lrow] = f2bf(acc[mf][nf][r]);
            }
        }
}

// ---------------- aggregate v4: 8 edges/iter, 2 gathers in flight ----------------
__global__ __launch_bounds__(256)
void aggregate_v4(const unsigned short* __restrict__ h16, const int2* __restrict__ pay,
                  const int* __restrict__ offsets,
                  const float* __restrict__ dinv, const float* __restrict__ bias,
                  float* __restrict__ out, int n) {
    int wid  = (blockIdx.x * blockDim.x + threadIdx.x) >> 6;
    int lane = threadIdx.x & 63;
    if (wid >= n) return;
    const int g  = lane >> 4;          // edge subgroup 0..3
    const int f4 = (lane & 15) * 4;    // feature base

    float a0 = 0.f, a1 = 0.f, a2 = 0.f, a3 = 0.f;
    int beg = offsets[wid], end = offsets[wid + 1];
    int cnt = end - beg;
    int nq  = cnt >> 3;
    int e   = beg + g;
#pragma unroll 2
    for (int q = 0; q < nq; ++q, e += 8) {
        int2 p1 = pay[e];
        int2 p2 = pay[e + 4];
        float w1 = __int_as_float(p1.y);
        float w2 = __int_as_float(p2.y);
        ushort4 h1 = *(const ushort4*)(h16 + (size_t)p1.x * HID + f4);
        ushort4 h2 = *(const ushort4*)(h16 + (size_t)p2.x * HID + f4);
        a0 = fmaf(bf2f(h1.x), w1, a0); a1 = fmaf(bf2f(h1.y), w1, a1);
        a2 = fmaf(bf2f(h1.z), w1, a2); a3 = fmaf(bf2f(h1.w), w1, a3);
        a0 = fmaf(bf2f(h2.x), w2, a0); a1 = fmaf(bf2f(h2.y), w2, a1);
        a2 = fmaf(bf2f(h2.z), w2, a2); a3 = fmaf(bf2f(h2.w), w2, a3);
    }
    int rem  = cnt & 7;
    int base = beg + nq * 8;
    if (g < rem) {
        int2  pw  = pay[base + g];
        float wgt = __int_as_float(pw.y);
        ushort4 hv = *(const ushort4*)(h16 + (size_t)pw.x * HID + f4);
        a0 = fmaf(bf2f(hv.x), wgt, a0); a1 = fmaf(bf2f(hv.y), wgt, a1);
        a2 = fmaf(bf2f(hv.z), wgt, a2); a3 = fmaf(bf2f(hv.w), wgt, a3);
    }
    if (g + 4 < rem) {
        int2  pw  = pay[base + g + 4];
        float wgt = __int_as_float(pw.y);
        ushort4 hv = *(const ushort4*)(h16 + (size_t)pw.x * HID + f4);
        a0 = fmaf(bf2f(hv.x), wgt, a0); a1 = fmaf(bf2f(hv.y), wgt, a1);
        a2 = fmaf(bf2f(hv.z), wgt, a2); a3 = fmaf(bf2f(hv.w), wgt, a3);
    }
    if (g == 0) {   // self loop
        float di = dinv[wid];
        float w2 = di * di;
        ushort4 hv = *(const ushort4*)(h16 + (size_t)wid * HID + f4);
        a0 = fmaf(bf2f(hv.x), w2, a0); a1 = fmaf(bf2f(hv.y), w2, a1);
        a2 = fmaf(bf2f(hv.z), w2, a2); a3 = fmaf(bf2f(hv.w), w2, a3);
    }
    a0 += __shfl_xor(a0, 16); a0 += __shfl_xor(a0, 32);
    a1 += __shfl_xor(a1, 16); a1 += __shfl_xor(a1, 32);
    a2 += __shfl_xor(a2, 16); a2 += __shfl_xor(a2, 32);
    a3 += __shfl_xor(a3, 16); a3 += __shfl_xor(a3, 32);
    if (g == 0) {
        float4 bv = *(const float4*)&bias[f4];
        float4 o;
        o.x = fmaxf(a0 + bv.x, 0.f);
        o.y = fmaxf(a1 + bv.y, 0.f);
        o.z = fmaxf(a2 + bv.z, 0.f);
        o.w = fmaxf(a3 + bv.w, 0.f);
        *(float4*)&out[(size_t)wid * HID + f4] = o;
    }
}

// ---------------- fused MLP head via MFMA + butterfly log_softmax ----------------
__device__ __forceinline__ void split8(const float* v, short8v& h, short8v& l) {
    h = cvt8(v);
    float res[8];
#pragma unroll
    for (int j = 0; j < 8; ++j) res[j] = v[j] - bf2f((unsigned short)h[j]);
    l = cvt8(res);
}

__global__ __launch_bounds__(256)
void mlp_mfma(const float* __restrict__ y,
              const unsigned short* __restrict__ w1h, const unsigned short* __restrict__ w1l,
              const unsigned short* __restrict__ w2h, const unsigned short* __restrict__ w2l,
              const unsigned short* __restrict__ w3h, const unsigned short* __restrict__ w3l,
              const float* __restrict__ bf1, const float* __restrict__ bf2,
              const float* __restrict__ bf3,
              float* __restrict__ out, int M) {
    __shared__ float tbuf[4][32 * 64];
    const int t    = threadIdx.x;
    const int lane = t & 63;
    const int w    = t >> 6;
    const int m0   = blockIdx.x * 128 + w * 32;
    const int lrow = lane & 15;
    const int hi16 = lane >> 4;
    const int koff = hi16 * 8;
    float* tb = tbuf[w];

    float b1v[4], b2v[4];
#pragma unroll
    for (int nf = 0; nf < 4; ++nf) {
        b1v[nf] = bf1[nf * 16 + lrow];
        b2v[nf] = bf2[nf * 16 + lrow];
    }
    float b3v = (lrow < NCLS) ? bf3[lrow] : 0.f;

    short8v aH[2][2], aL[2][2];   // [mf][kt]
    {
        const float* a0 = y + (size_t)min(m0 + lrow,      M - 1) * 64;
        const float* a1 = y + (size_t)min(m0 + 16 + lrow, M - 1) * 64;
#pragma unroll
        for (int kt = 0; kt < 2; ++kt) {
            float v0[8], v1[8];
            __builtin_memcpy(v0, a0 + kt * 32 + koff, 32);
            __builtin_memcpy(v1, a1 + kt * 32 + koff, 32);
            split8(v0, aH[0][kt], aL[0][kt]);
            split8(v1, aH[1][kt], aL[1][kt]);
        }
    }

#pragma unroll
    for (int layer = 0; layer < 2; ++layer) {
        const unsigned short* wh = layer ? w2h : w1h;
        const unsigned short* wl = layer ? w2l : w1l;
        const float* bv = layer ? b2v : b1v;
        f32x4 acc[2][4];
#pragma unroll
        for (int i = 0; i < 2; ++i)
#pragma unroll
            for (int j = 0; j < 4; ++j) acc[i][j] = (f32x4){0.f, 0.f, 0.f, 0.f};
#pragma unroll
        for (int kt = 0; kt < 2; ++kt) {
            short8v bH[4], bL[4];
#pragma unroll
            for (int nf = 0; nf < 4; ++nf) {
                bH[nf] = *((const short8v*)wh + (kt * 4 + nf) * 64 + lane);
                bL[nf] = *((const short8v*)wl + (kt * 4 + nf) * 64 + lane);
            }
#pragma unroll
            for (int mf = 0; mf < 2; ++mf)
#pragma unroll
                for (int nf = 0; nf < 4; ++nf) {
                    acc[mf][nf] = __builtin_amdgcn_mfma_f32_16x16x32_bf16(aH[mf][kt], bH[nf], acc[mf][nf], 0, 0, 0);
                    acc[mf][nf] = __builtin_amdgcn_mfma_f32_16x16x32_bf16(aH[mf][kt], bL[nf], acc[mf][nf], 0, 0, 0);
                    acc[mf][nf] = __builtin_amdgcn_mfma_f32_16x16x32_bf16(aL[mf][kt], bH[nf], acc[mf][nf], 0, 0, 0);
                }
        }
#pragma unroll
        for (int mf = 0; mf < 2; ++mf)
#pragma unroll
            for (int nf = 0; nf < 4; ++nf)
#pragma unroll
                for (int r = 0; r < 4; ++r) {
                    int row = mf * 16 + hi16 * 4 + r;
                    int col = nf * 16 + lrow;
                    float v = fmaxf(acc[mf][nf][r] + bv[nf], 0.f);
                    *(float*)((char*)tb + ((((row << 6) + col) << 2) ^ ((row & 3) << 5))) = v;
                }
#pragma unroll
        for (int mf = 0; mf < 2; ++mf)
#pragma unroll
            for (int kt = 0; kt < 2; ++kt) {
                int row = mf * 16 + lrow;
                float v[8];
                __builtin_memcpy(v, (char*)tb + ((((row << 6) + kt * 32 + koff) << 2) ^ ((row & 3) << 5)), 32);
                split8(v, aH[mf][kt], aL[mf][kt]);
            }
    }

    f32x4 acc3[2];
    acc3[0] = (f32x4){0.f, 0.f, 0.f, 0.f};
    acc3[1] = (f32x4){0.f, 0.f, 0.f, 0.f};
#pragma unroll
    for (int kt = 0; kt < 2; ++kt) {
        short8v bH = *((const short8v*)w3h + kt * 64 + lane);
        short8v bL = *((const short8v*)w3l + kt * 64 + lane);
#pragma unroll
        for (int mf = 0; mf < 2; ++mf) {
            acc3[mf] = __builtin_amdgcn_mfma_f32_16x16x32_bf16(aH[mf][kt], bH, acc3[mf], 0, 0, 0);
            acc3[mf] = __builtin_amdgcn_mfma_f32_16x16x32_bf16(aH[mf][kt], bL, acc3[mf], 0, 0, 0);
            acc3[mf] = __builtin_amdgcn_mfma_f32_16x16x32_bf16(aL[mf][kt], bH, acc3[mf], 0, 0, 0);
        }
    }
#pragma unroll
    for (int mf = 0; mf < 2; ++mf)
#pragma unroll
        for (int r = 0; r < 4; ++r) {
            float z  = acc3[mf][r] + b3v;
            float zm = (lrow < NCLS) ? z : -1e30f;
            float m  = zm;
#pragma unroll
            for (int mask = 1; mask < 16; mask <<= 1)
                m = fmaxf(m, __shfl_xor(m, mask));
            float ev = (lrow < NCLS) ? expf(z - m) : 0.f;
            float ss = ev;
#pragma unroll
            for (int mask = 1; mask < 16; mask <<= 1)
                ss += __shfl_xor(ss, mask);
            float res = z - (m + logf(ss));
            int row = m0 + mf * 16 + hi16 * 4 + r;
            if (row < M && lrow < NCLS)
                out[(size_t)row * NCLS + lrow] = res;
        }
}

extern "C" void kernel_launch(void* const* d_in, const int* in_sizes, int n_in,
                              void* d_out, int out_size, void* d_ws, size_t ws_size,
                              hipStream_t stream) {
    const float* x   = (const float*)d_in[0];
    const int*   ei  = (const int*)d_in[1];
    const float* W1  = (const float*)d_in[2];
    const float* b1  = (const float*)d_in[3];
    const float* W2  = (const float*)d_in[4];
    const float* b2  = (const float*)d_in[5];
    const float* Wf1 = (const float*)d_in[6];
    const float* bf1 = (const float*)d_in[7];
    const float* Wf2 = (const float*)d_in[8];
    const float* bf2 = (const float*)d_in[9];
    const float* Wf3 = (const float*)d_in[10];
    const float* bf3 = (const float*)d_in[11];

    const int N = N_NODES;
    const int E = in_sizes[1] / 2;
    float* outp = (float*)d_out;

    char* p = (char*)d_ws;
    auto alloc = [&](size_t bytes) {
        char* q = p;
        p += (bytes + 255) & ~(size_t)255;
        return q;
    };
    int*            counts   = (int*)           alloc((size_t)N * 4);
    int*            offsets  = (int*)           alloc((size_t)(N + 1) * 4);
    int*            cursor   = (int*)           alloc((size_t)N * 4);
    int*            local_ex = (int*)           alloc((size_t)N * 4);
    int*            blocksum = (int*)           alloc((size_t)NBLK * 4);
    int*            blockoff = (int*)           alloc((size_t)NBLK * 4);
    float*          dinv     = (float*)         alloc((size_t)N * 4);
    int2*           pay      = (int2*)          alloc((size_t)E * 8);
    unsigned short* w1fh     = (unsigned short*)alloc((size_t)NKT1 * 4 * 64 * 8 * 2);
    unsigned short* w1fl     = (unsigned short*)alloc((size_t)NKT1 * 4 * 64 * 8 * 2);
    unsigned short* w2fh     = (unsigned short*)alloc((size_t)2 * 4 * 64 * 8 * 2);
    unsigned short* w2fl     = (unsigned short*)alloc((size_t)2 * 4 * 64 * 8 * 2);
    unsigned short* wf1h     = (unsigned short*)alloc((size_t)2 * 4 * 64 * 8 * 2);
    unsigned short* wf1l     = (unsigned short*)alloc((size_t)2 * 4 * 64 * 8 * 2);
    unsigned short* wf2h     = (unsigned short*)alloc((size_t)2 * 4 * 64 * 8 * 2);
    unsigned short* wf2l     = (unsigned short*)alloc((size_t)2 * 4 * 64 * 8 * 2);
    unsigned short* wf3h     = (unsigned short*)alloc((size_t)2 * 1 * 64 * 8 * 2);
    unsigned short* wf3l     = (unsigned short*)alloc((size_t)2 * 1 * 64 * 8 * 2);
    unsigned short* bufH16   = (unsigned short*)alloc((size_t)N * HID * 2);
    float*          bufF     = (float*)         alloc((size_t)N * HID * 4);

    const int* src = ei;
    const int* dst = ei + E;

    hipMemsetAsync(counts, 0, (size_t)N * 4, stream);
    int ge = (E + 255) / 256;     // 12500 hist/scatter blocks
    int GB = (N + 63) / 64;       // 1563 gemm blocks (64 rows each)

    // [w-converts | hist]
    prep1<<<WCV_BLKS + ge, 256, 0, stream>>>(W1, w1fh, w1fl, W2, w2fh, w2fl,
                                             Wf1, wf1h, wf1l, Wf2, wf2h, wf2l,
                                             Wf3, wf3h, wf3l, dst, counts, E);
    scan_p1d<<<NBLK, SCAN_BLK, 0, stream>>>(counts, local_ex, blocksum, dinv, N);
    scan_p2<<<1, 128, 0, stream>>>(blocksum, blockoff, &offsets[N], NBLK);
    scan_p3<<<NBLK, SCAN_BLK, 0, stream>>>(local_ex, blockoff, offsets, cursor, N);

    // [gemm layer1 (counted-vmcnt pipeline) | scatter]
    mega2<<<GB + ge, 256, 0, stream>>>(x, w1fh, bufH16, N, GB,
                                       src, dst, dinv, cursor, pay, E);

    aggregate_v4<<<(N + 3) / 4, 256, 0, stream>>>(bufH16, pay, offsets, dinv, b1, bufF, N);
    gemm_hid_v3<<<(N + 127) / 128, 256, 0, stream>>>(bufF, w2fh, w2fl, bufH16, N);
    aggregate_v4<<<(N + 3) / 4, 256, 0, stream>>>(bufH16, pay, offsets, dinv, b2, bufF, N);
    mlp_mfma<<<(N + 127) / 128, 256, 0, stream>>>(bufF, wf1h, wf1l, wf2h, wf2l, wf3h, wf3l,
                                                  bf1, bf2, bf3, outp, N);
}